// Round 5
// baseline (464.548 us; speedup 1.0000x reference)
//
#include <hip/hip_runtime.h>

#define NN 50000
#define NE 800000
#define NG 2048
#define F 64
#define SBLK 4
#define SRCDIV 12500            // nodes per src block (slice = 12500*256B = 3.2MB < 4MB L2/XCD)
#define M2 (NN * SBLK)          // 200000 (dst,block) segments

constexpr int NB2 = (M2 + 255) / 256;   // 782 scan blocks

typedef float f4 __attribute__((ext_vector_type(4)));

static __device__ __forceinline__ f4 ntload(const f4* p) {
    return __builtin_nontemporal_load(p);
}
static __device__ __forceinline__ void ntstore(f4* p, f4 v) {
    __builtin_nontemporal_store(v, p);
}

// ---------------- deg2: count edges per (dst, src_block) ----------------
__global__ void deg2_kernel(const int* __restrict__ src, const int* __restrict__ dst,
                            int* __restrict__ deg2) {
    int e = blockIdx.x * 256 + threadIdx.x;
    if (e < NE) {
        int blk = src[e] / SRCDIV;
        atomicAdd(&deg2[dst[e] * SBLK + blk], 1);
    }
}

// dinv[v] = rsqrt(total_deg + 1)
__global__ void dinv_kernel(const int* __restrict__ deg2, float* __restrict__ dinv) {
    int v = blockIdx.x * 256 + threadIdx.x;
    if (v < NN) {
        const int4 d4 = ((const int4*)deg2)[v];
        dinv[v] = rsqrtf((float)(d4.x + d4.y + d4.z + d4.w + 1));
    }
}

// xd[v] = dinv[v] * x[v]   (32 feats as 8 float4 per row)
__global__ void scalex_kernel(const float4* __restrict__ x4, const float* __restrict__ dinv,
                              float4* __restrict__ xd4) {
    int i = blockIdx.x * 256 + threadIdx.x;
    if (i < NN * 8) {
        int v = i >> 3;
        float d = dinv[v];
        float4 a = x4[i];
        a.x *= d; a.y *= d; a.z *= d; a.w *= d;
        xd4[i] = a;
    }
}

// ---------------- 3-kernel exclusive scan of deg2[M2] -> rowptr2 ----------------
__global__ void scan1_kernel(const int* __restrict__ deg2, int* __restrict__ bsums) {
    __shared__ int s[256];
    int t = threadIdx.x, i = blockIdx.x * 256 + t;
    s[t] = (i < M2) ? deg2[i] : 0;
    __syncthreads();
    for (int off = 128; off > 0; off >>= 1) {
        if (t < off) s[t] += s[t + off];
        __syncthreads();
    }
    if (t == 0) bsums[blockIdx.x] = s[0];
}

__global__ void scan2_kernel(int* __restrict__ bsums, int* __restrict__ rowptr2) {
    __shared__ int s[1024];
    int t = threadIdx.x;
    int v = (t < NB2) ? bsums[t] : 0;
    s[t] = v;
    __syncthreads();
    for (int off = 1; off < 1024; off <<= 1) {
        int x = (t >= off) ? s[t - off] : 0;
        __syncthreads();
        s[t] += x;
        __syncthreads();
    }
    if (t < NB2) bsums[t] = s[t] - v;   // exclusive block offset
    if (t == 0) rowptr2[M2] = NE;
}

__global__ void scan3_kernel(const int* __restrict__ deg2, const int* __restrict__ bsums,
                             int* __restrict__ rowptr2, int* __restrict__ cursor2) {
    __shared__ int s[256];
    int t = threadIdx.x, i = blockIdx.x * 256 + t;
    int v = (i < M2) ? deg2[i] : 0;
    s[t] = v;
    __syncthreads();
    for (int off = 1; off < 256; off <<= 1) {
        int x = (t >= off) ? s[t - off] : 0;
        __syncthreads();
        s[t] += x;
        __syncthreads();
    }
    if (i < M2) {
        int rp = bsums[blockIdx.x] + s[t] - v;
        rowptr2[i] = rp;
        cursor2[i] = rp;
    }
}

// scatter edges into segmented CSR slots
__global__ void fill_kernel(const int* __restrict__ src, const int* __restrict__ dst,
                            int* __restrict__ cursor2, int* __restrict__ col) {
    int e = blockIdx.x * 256 + threadIdx.x;
    if (e < NE) {
        int s = src[e];
        int slot = atomicAdd(&cursor2[dst[e] * SBLK + s / SRCDIV], 1);
        col[slot] = s;
    }
}

// ---------------- layer-1 src-blocked aggregation pass (32 feats = 8 f4) ----------
// acc across passes in-place; FIRST seeds with self term; LAST applies dinv.
// 8 slots x 8 f4-lanes; 8 edges per iteration.
template <bool FIRST, bool LAST>
__global__ void agg32_pass(const f4* __restrict__ g4, const int* __restrict__ rowptr2,
                           const int* __restrict__ col, const float* __restrict__ dinv,
                           f4* __restrict__ acc4, int p) {
    int lane = threadIdx.x & 63;
    int v = blockIdx.x * 4 + (threadIdx.x >> 6);
    int slot = lane >> 3, fq = lane & 7;
    long rowbase = (long)v * 8 + fq;
    f4 prev = FIRST ? g4[rowbase] : ntload(&acc4[rowbase]);   // self term / running sum
    int beg = rowptr2[v * SBLK + p], end = rowptr2[v * SBLK + p + 1];
    f4 part = {0.f, 0.f, 0.f, 0.f};
    for (int base = beg; base < end; base += 8) {
        int e = base + slot;
        int ce = (e < end) ? e : end - 1;
        float w = (e < end) ? 1.f : 0.f;
        int u = col[ce];
        part += w * g4[(long)u * 8 + fq];   // slice-p resident gather
    }
#pragma unroll
    for (int m = 8; m < 64; m <<= 1) {
        part.x += __shfl_xor(part.x, m);
        part.y += __shfl_xor(part.y, m);
        part.z += __shfl_xor(part.z, m);
        part.w += __shfl_xor(part.w, m);
    }
    f4 val = prev + part;
    if (!LAST) {
        if (slot == 0) ntstore(&acc4[rowbase], val);
    } else {
        if (slot == 0) acc4[rowbase] = dinv[v] * val;
    }
}

// ---------------- src-blocked aggregation pass (64 feats = 16 f4) ------------------
// LAST: h = relu(dinv*acc + b), optionally fused pool atomics.
template <bool FIRST, bool LAST, bool POOL>
__global__ void agg4_pass(const f4* __restrict__ g4, const int* __restrict__ rowptr2,
                          const int* __restrict__ col, const float* __restrict__ dinv,
                          const f4* __restrict__ bias4, f4* __restrict__ acc4, int p,
                          const int* __restrict__ batch, float* __restrict__ pooled,
                          float* __restrict__ counts) {
    int lane = threadIdx.x & 63;
    int v = blockIdx.x * 4 + (threadIdx.x >> 6);
    int slot = lane >> 4, fq = lane & 15;
    long rowbase = (long)v * 16 + fq;
    f4 prev = FIRST ? g4[rowbase] : ntload(&acc4[rowbase]);   // self term / running sum
    int beg = rowptr2[v * SBLK + p], end = rowptr2[v * SBLK + p + 1];
    f4 part = {0.f, 0.f, 0.f, 0.f};
    for (int base = beg; base < end; base += 8) {
#pragma unroll
        for (int j = 0; j < 2; ++j) {
            int e = base + slot + j * 4;
            int ce = (e < end) ? e : end - 1;
            float w = (e < end) ? 1.f : 0.f;
            int u = col[ce];
            part += w * g4[(long)u * 16 + fq];   // slice-p resident gather
        }
    }
#pragma unroll
    for (int m = 16; m < 64; m <<= 1) {
        part.x += __shfl_xor(part.x, m);
        part.y += __shfl_xor(part.y, m);
        part.z += __shfl_xor(part.z, m);
        part.w += __shfl_xor(part.w, m);
    }
    f4 val = prev + part;
    if (!LAST) {
        if (slot == 0) ntstore(&acc4[rowbase], val);
    } else {
        float d = dinv[v];
        f4 bb = bias4[fq];
        f4 hv;
        hv.x = fmaxf(fmaf(d, val.x, bb.x), 0.f);
        hv.y = fmaxf(fmaf(d, val.y, bb.y), 0.f);
        hv.z = fmaxf(fmaf(d, val.z, bb.z), 0.f);
        hv.w = fmaxf(fmaf(d, val.w, bb.w), 0.f);
        if (slot == 0) {
            if (POOL) {
                int b = batch[v];
                float* pp = pooled + (long)b * F + fq * 4;
                atomicAdd(pp + 0, hv.x);
                atomicAdd(pp + 1, hv.y);
                atomicAdd(pp + 2, hv.z);
                atomicAdd(pp + 3, hv.w);
                if (lane == 0) atomicAdd(&counts[b], 1.0f);
            } else {
                acc4[rowbase] = hv;
            }
        }
    }
}

// ---------------- GEMM: 16 nodes/block, 256 threads -------------------------------
template <int K, bool RELU_BIAS>
__global__ void gemm_kernel(const float* __restrict__ in, const float* __restrict__ W,
                            const float* __restrict__ bias, const float* __restrict__ dinv,
                            float* __restrict__ out) {
    __shared__ float Ws[K * F];
    int t = threadIdx.x;
#pragma unroll
    for (int i = 0; i < K * F / 256; ++i) Ws[i * 256 + t] = W[i * 256 + t];
    __syncthreads();
    int f = t & 63;
    int slot = __builtin_amdgcn_readfirstlane(t >> 6);  // wave-uniform
    int n0 = blockIdx.x * 16 + slot;                    // nodes n0, n0+4, n0+8, n0+12
    float acc0 = 0.f, acc1 = 0.f, acc2 = 0.f, acc3 = 0.f;
    const float* r0 = in + (long)n0 * K;
    const float* r1 = r0 + 4 * K;
    const float* r2 = r0 + 8 * K;
    const float* r3 = r0 + 12 * K;
#pragma unroll
    for (int k = 0; k < K; ++k) {
        float w = Ws[k * F + f];
        acc0 = fmaf(r0[k], w, acc0);
        acc1 = fmaf(r1[k], w, acc1);
        acc2 = fmaf(r2[k], w, acc2);
        acc3 = fmaf(r3[k], w, acc3);
    }
    if (RELU_BIAS) {
        float b = bias[f];
        out[(long)n0 * F + f]        = fmaxf(acc0 + b, 0.f);
        out[(long)(n0 + 4) * F + f]  = fmaxf(acc1 + b, 0.f);
        out[(long)(n0 + 8) * F + f]  = fmaxf(acc2 + b, 0.f);
        out[(long)(n0 + 12) * F + f] = fmaxf(acc3 + b, 0.f);
    } else {
        out[(long)n0 * F + f]        = dinv[n0] * acc0;
        out[(long)(n0 + 4) * F + f]  = dinv[n0 + 4] * acc1;
        out[(long)(n0 + 8) * F + f]  = dinv[n0 + 8] * acc2;
        out[(long)(n0 + 12) * F + f] = dinv[n0 + 12] * acc3;
    }
}

// ---------------- head: out = relu(pooled/cnt @ lw1 + lb1) @ lw2 + lb2 ----------------
__global__ void head_kernel(const float* __restrict__ pooled, const float* __restrict__ counts,
                            const float* __restrict__ lw1, const float* __restrict__ lb1,
                            const float* __restrict__ lw2, const float* __restrict__ lb2,
                            float* __restrict__ out) {
    __shared__ float p[F];
    __shared__ float hid[F];
    int gid = blockIdx.x, t = threadIdx.x;
    float cnt = fmaxf(counts[gid], 1.0f);
    p[t] = pooled[(long)gid * F + t] / cnt;
    __syncthreads();
    float acc = lb1[t];
#pragma unroll 8
    for (int k = 0; k < F; ++k) acc = fmaf(p[k], lw1[k * F + t], acc);
    hid[t] = fmaxf(acc, 0.f);
    __syncthreads();
    if (t < 2) {
        float a = lb2[t];
#pragma unroll 8
        for (int k = 0; k < F; ++k) a = fmaf(hid[k], lw2[k * 2 + t], a);
        out[(long)gid * 2 + t] = a;
    }
}

extern "C" void kernel_launch(void* const* d_in, const int* in_sizes, int n_in,
                              void* d_out, int out_size, void* d_ws, size_t ws_size,
                              hipStream_t stream) {
    const float* x    = (const float*)d_in[0];
    const int*   ei   = (const int*)d_in[1];   // [2, NE]: src then dst
    const int*   bat  = (const int*)d_in[2];
    const float* W1   = (const float*)d_in[3];
    const float* b1   = (const float*)d_in[4];
    const float* W2   = (const float*)d_in[5];
    const float* b2   = (const float*)d_in[6];
    const float* W3   = (const float*)d_in[7];
    const float* b3   = (const float*)d_in[8];
    const float* lw1  = (const float*)d_in[9];
    const float* lb1  = (const float*)d_in[10];
    const float* lw2  = (const float*)d_in[11];
    const float* lb2  = (const float*)d_in[12];
    float* out = (float*)d_out;

    const int* src = ei;
    const int* dst = ei + NE;

    // workspace carve-up (256B aligned)
    char* ws = (char*)d_ws;
    size_t off = 0;
    auto carve = [&](size_t bytes) {
        void* p = ws + off;
        off += (bytes + 255) & ~(size_t)255;
        return p;
    };
    int*   deg2    = (int*)carve((size_t)M2 * 4);
    float* dinv    = (float*)carve(NN * 4);
    int*   rowptr2 = (int*)carve((size_t)(M2 + 1) * 4);
    int*   cursor2 = (int*)carve((size_t)M2 * 4);
    int*   bsums   = (int*)carve(1024 * 4);
    int*   col     = (int*)carve((size_t)NE * 4);
    float* xd      = (float*)carve((size_t)NN * 32 * 4);
    float* sbuf    = (float*)carve((size_t)NN * 32 * 4);
    float* bufA    = (float*)carve((size_t)NN * F * 4);
    float* bufB    = (float*)carve((size_t)NN * F * 4);
    float* pooled  = (float*)carve((size_t)NG * F * 4 + NG * 4);
    float* counts  = pooled + (size_t)NG * F;

    hipMemsetAsync(deg2, 0, (size_t)M2 * 4, stream);
    hipMemsetAsync(pooled, 0, ((size_t)NG * F + NG) * 4, stream);

    deg2_kernel<<<(NE + 255) / 256, 256, 0, stream>>>(src, dst, deg2);
    dinv_kernel<<<(NN + 255) / 256, 256, 0, stream>>>(deg2, dinv);
    scalex_kernel<<<(NN * 8 + 255) / 256, 256, 0, stream>>>((const float4*)x, dinv, (float4*)xd);
    scan1_kernel<<<NB2, 256, 0, stream>>>(deg2, bsums);
    scan2_kernel<<<1, 1024, 0, stream>>>(bsums, rowptr2);
    scan3_kernel<<<NB2, 256, 0, stream>>>(deg2, bsums, rowptr2, cursor2);
    fill_kernel<<<(NE + 255) / 256, 256, 0, stream>>>(src, dst, cursor2, col);

    const int gridN = (NN + 3) / 4;    // 12500 blocks, 4 nodes (waves) each
    const int gridG = NN / 16;         // 3125 blocks for gemm

    // layer 1: src-blocked aggregation of xd -> sbuf, then GEMM (+bias+relu)
    agg32_pass<true,  false><<<gridN, 256, 0, stream>>>((const f4*)xd, rowptr2, col, dinv, (f4*)sbuf, 0);
    agg32_pass<false, false><<<gridN, 256, 0, stream>>>((const f4*)xd, rowptr2, col, dinv, (f4*)sbuf, 1);
    agg32_pass<false, false><<<gridN, 256, 0, stream>>>((const f4*)xd, rowptr2, col, dinv, (f4*)sbuf, 2);
    agg32_pass<false, true ><<<gridN, 256, 0, stream>>>((const f4*)xd, rowptr2, col, dinv, (f4*)sbuf, 3);
    gemm_kernel<32, true><<<gridG, 256, 0, stream>>>(sbuf, W1, b1, dinv, bufA);

    // layer 2: g2 = dinv*(h1@W2) in bufB; blocked agg into bufA (h2)
    gemm_kernel<64, false><<<gridG, 256, 0, stream>>>(bufA, W2, nullptr, dinv, bufB);
    agg4_pass<true,  false, false><<<gridN, 256, 0, stream>>>((const f4*)bufB, rowptr2, col, dinv,
                                                              (const f4*)b2, (f4*)bufA, 0, nullptr, nullptr, nullptr);
    agg4_pass<false, false, false><<<gridN, 256, 0, stream>>>((const f4*)bufB, rowptr2, col, dinv,
                                                              (const f4*)b2, (f4*)bufA, 1, nullptr, nullptr, nullptr);
    agg4_pass<false, false, false><<<gridN, 256, 0, stream>>>((const f4*)bufB, rowptr2, col, dinv,
                                                              (const f4*)b2, (f4*)bufA, 2, nullptr, nullptr, nullptr);
    agg4_pass<false, true,  false><<<gridN, 256, 0, stream>>>((const f4*)bufB, rowptr2, col, dinv,
                                                              (const f4*)b2, (f4*)bufA, 3, nullptr, nullptr, nullptr);

    // layer 3: g3 = dinv*(h2@W3) in bufB; blocked agg, final pass fuses mean-pool atomics
    gemm_kernel<64, false><<<gridG, 256, 0, stream>>>(bufA, W3, nullptr, dinv, bufB);
    agg4_pass<true,  false, false><<<gridN, 256, 0, stream>>>((const f4*)bufB, rowptr2, col, dinv,
                                                              (const f4*)b3, (f4*)bufA, 0, nullptr, nullptr, nullptr);
    agg4_pass<false, false, false><<<gridN, 256, 0, stream>>>((const f4*)bufB, rowptr2, col, dinv,
                                                              (const f4*)b3, (f4*)bufA, 1, nullptr, nullptr, nullptr);
    agg4_pass<false, false, false><<<gridN, 256, 0, stream>>>((const f4*)bufB, rowptr2, col, dinv,
                                                              (const f4*)b3, (f4*)bufA, 2, nullptr, nullptr, nullptr);
    agg4_pass<false, true,  true ><<<gridN, 256, 0, stream>>>((const f4*)bufB, rowptr2, col, dinv,
                                                              (const f4*)b3, (f4*)bufA, 3, bat, pooled, counts);

    // head MLP
    head_kernel<<<NG, 64, 0, stream>>>(pooled, counts, lw1, lb1, lw2, lb2, out);
}

// Round 6
// 324.174 us; speedup vs baseline: 1.4330x; 1.4330x over previous
//
#include <hip/hip_runtime.h>

#define NN 50000
#define NE 800000
#define NG 2048
#define F 64

constexpr int SCAN_B = 256;
constexpr int NB = (NN + SCAN_B - 1) / SCAN_B;  // 196 blocks

typedef float f4 __attribute__((ext_vector_type(4)));

// ---------------- degree (edge-only in-degree) ----------------
__global__ void deg_kernel(const int* __restrict__ dst, int* __restrict__ deg) {
    int e = blockIdx.x * 256 + threadIdx.x;
    if (e < NE) atomicAdd(&deg[dst[e]], 1);
}

// dinv[v] = rsqrt(deg_edges[v] + 1)   (+1 = self loop)
__global__ void dinv_kernel(const int* __restrict__ deg, float* __restrict__ dinv) {
    int v = blockIdx.x * 256 + threadIdx.x;
    if (v < NN) dinv[v] = rsqrtf((float)(deg[v] + 1));
}

// xd[v] = dinv[v] * x[v]   (32 feats as 8 float4 per row)
__global__ void scalex_kernel(const float4* __restrict__ x4, const float* __restrict__ dinv,
                              float4* __restrict__ xd4) {
    int i = blockIdx.x * 256 + threadIdx.x;
    if (i < NN * 8) {
        int v = i >> 3;
        float d = dinv[v];
        float4 a = x4[i];
        a.x *= d; a.y *= d; a.z *= d; a.w *= d;
        xd4[i] = a;
    }
}

// ---------------- 3-kernel exclusive scan of deg -> rowptr ----------------
__global__ void scan1_kernel(const int* __restrict__ deg, int* __restrict__ bsums) {
    __shared__ int s[256];
    int t = threadIdx.x, i = blockIdx.x * 256 + t;
    s[t] = (i < NN) ? deg[i] : 0;
    __syncthreads();
    for (int off = 128; off > 0; off >>= 1) {
        if (t < off) s[t] += s[t + off];
        __syncthreads();
    }
    if (t == 0) bsums[blockIdx.x] = s[0];
}

__global__ void scan2_kernel(int* __restrict__ bsums, int* __restrict__ rowptr) {
    __shared__ int s[256];
    int t = threadIdx.x;
    int v = (t < NB) ? bsums[t] : 0;
    s[t] = v;
    __syncthreads();
    for (int off = 1; off < 256; off <<= 1) {
        int x = (t >= off) ? s[t - off] : 0;
        __syncthreads();
        s[t] += x;
        __syncthreads();
    }
    if (t < NB) bsums[t] = s[t] - v;   // exclusive block offset
    if (t == 0) rowptr[NN] = NE;
}

__global__ void scan3_kernel(const int* __restrict__ deg, const int* __restrict__ bsums,
                             int* __restrict__ rowptr, int* __restrict__ cursor) {
    __shared__ int s[256];
    int t = threadIdx.x, i = blockIdx.x * 256 + t;
    int v = (i < NN) ? deg[i] : 0;
    s[t] = v;
    __syncthreads();
    for (int off = 1; off < 256; off <<= 1) {
        int x = (t >= off) ? s[t - off] : 0;
        __syncthreads();
        s[t] += x;
        __syncthreads();
    }
    if (i < NN) {
        int rp = bsums[blockIdx.x] + s[t] - v;
        rowptr[i] = rp;
        cursor[i] = rp;
    }
}

// scatter edges into CSR slots (order within a row irrelevant)
__global__ void fill_kernel(const int* __restrict__ src, const int* __restrict__ dst,
                            int* __restrict__ cursor, int* __restrict__ col) {
    int e = blockIdx.x * 256 + threadIdx.x;
    if (e < NE) {
        int slot = atomicAdd(&cursor[dst[e]], 1);
        col[slot] = src[e];
    }
}

// ---------------- layer-1 aggregation over raw xd (32 feats = 8 f4) ------------
// s[v] = dinv[v] * (sum_{u->v} xd[u] + xd[v])
// 8 slots x 8 f4-lanes; 32-edge batches, all gathers in flight.
__global__ void agg32_kernel(const f4* __restrict__ g4, const int* __restrict__ rowptr,
                             const int* __restrict__ col, const float* __restrict__ dinv,
                             float* __restrict__ out) {
    int lane = threadIdx.x & 63;
    int v = blockIdx.x * 4 + (threadIdx.x >> 6);
    int slot = lane >> 3, fq = lane & 7;
    int beg = rowptr[v], end = rowptr[v + 1];
    f4 acc = {0.f, 0.f, 0.f, 0.f};
    for (int base = beg; base < end; base += 32) {
        f4 a[4];
        float w[4];
#pragma unroll
        for (int j = 0; j < 4; ++j) {
            int e = base + slot + j * 8;
            int ce = (e < end) ? e : (end - 1);
            w[j] = (e < end) ? 1.f : 0.f;
            int u = col[ce];
            a[j] = g4[(long)u * 8 + fq];
        }
#pragma unroll
        for (int j = 0; j < 4; ++j) acc += w[j] * a[j];
    }
    // reduce across 8 slots (lane bits 3,4,5)
#pragma unroll
    for (int m = 8; m < 64; m <<= 1) {
        acc.x += __shfl_xor(acc.x, m);
        acc.y += __shfl_xor(acc.y, m);
        acc.z += __shfl_xor(acc.z, m);
        acc.w += __shfl_xor(acc.w, m);
    }
    f4 self = g4[(long)v * 8 + fq];
    float d = dinv[v];
    acc = d * (acc + self);
    // unpredicated-ish store: slots 0-3 write 32 distinct scalars = one 128B line
    if (slot < 4) {
        float comp = (slot == 0) ? acc.x : (slot == 1) ? acc.y : (slot == 2) ? acc.z : acc.w;
        out[(long)v * 32 + 4 * fq + slot] = comp;
    }
}

// ---------------- aggregation (64 feats = 16 f4), optional pool fuse ----------
// h[v] = relu(dinv[v]*(sum_{u->v} g[u] + g[v]) + b)
// 4 slots x 16 f4-lanes; 32-edge batches, all gathers in flight.
// Store: ALL 64 lanes write one distinct scalar (feature 4*fq+slot) -> no write amp.
template <bool POOL>
__global__ void agg4_kernel(const f4* __restrict__ g4, const int* __restrict__ rowptr,
                            const int* __restrict__ col, const float* __restrict__ dinv,
                            const f4* __restrict__ bias4, float* __restrict__ out,
                            const int* __restrict__ batch, float* __restrict__ pooled,
                            float* __restrict__ counts) {
    int lane = threadIdx.x & 63;
    int v = blockIdx.x * 4 + (threadIdx.x >> 6);
    int slot = lane >> 4, fq = lane & 15;
    int beg = rowptr[v], end = rowptr[v + 1];
    f4 acc = {0.f, 0.f, 0.f, 0.f};
    for (int base = beg; base < end; base += 32) {
        f4 a[8];
        float w[8];
#pragma unroll
        for (int j = 0; j < 8; ++j) {
            int e = base + slot + j * 4;
            int ce = (e < end) ? e : (end - 1);
            w[j] = (e < end) ? 1.f : 0.f;
            int u = col[ce];
            a[j] = g4[(long)u * 16 + fq];
        }
#pragma unroll
        for (int j = 0; j < 8; ++j) acc += w[j] * a[j];
    }
    // reduce across 4 slots (lane bits 4,5)
#pragma unroll
    for (int m = 16; m < 64; m <<= 1) {
        acc.x += __shfl_xor(acc.x, m);
        acc.y += __shfl_xor(acc.y, m);
        acc.z += __shfl_xor(acc.z, m);
        acc.w += __shfl_xor(acc.w, m);
    }
    f4 self = g4[(long)v * 16 + fq];
    float d = dinv[v];
    f4 bb = bias4[fq];
    f4 hv;
    hv.x = fmaxf(fmaf(d, acc.x + self.x, bb.x), 0.f);
    hv.y = fmaxf(fmaf(d, acc.y + self.y, bb.y), 0.f);
    hv.z = fmaxf(fmaf(d, acc.z + self.z, bb.z), 0.f);
    hv.w = fmaxf(fmaf(d, acc.w + self.w, bb.w), 0.f);
    float comp = (slot == 0) ? hv.x : (slot == 1) ? hv.y : (slot == 2) ? hv.z : hv.w;
    if (POOL) {
        int b = batch[v];
        atomicAdd(&pooled[(long)b * F + 4 * fq + slot], comp);  // 1 scalar atomic per lane
        if (lane == 0) atomicAdd(&counts[b], 1.0f);
    } else {
        out[(long)v * F + 4 * fq + slot] = comp;  // 64 lanes, 64 distinct scalars, 256B region
    }
}

// ---------------- GEMM: 16 nodes/block, 256 threads -------------------------------
// RELU_BIAS: out = relu(in@W + b)          (layer-1 path, K=32)
// else:      out = dinv[n] * (in@W)        (pre-aggregation scaling, K=64)
template <int K, bool RELU_BIAS>
__global__ void gemm_kernel(const float* __restrict__ in, const float* __restrict__ W,
                            const float* __restrict__ bias, const float* __restrict__ dinv,
                            float* __restrict__ out) {
    __shared__ float Ws[K * F];
    int t = threadIdx.x;
#pragma unroll
    for (int i = 0; i < K * F / 256; ++i) Ws[i * 256 + t] = W[i * 256 + t];
    __syncthreads();
    int f = t & 63;
    int slot = __builtin_amdgcn_readfirstlane(t >> 6);  // wave-uniform
    int n0 = blockIdx.x * 16 + slot;                    // nodes n0, n0+4, n0+8, n0+12
    float acc0 = 0.f, acc1 = 0.f, acc2 = 0.f, acc3 = 0.f;
    const float* r0 = in + (long)n0 * K;
    const float* r1 = r0 + 4 * K;
    const float* r2 = r0 + 8 * K;
    const float* r3 = r0 + 12 * K;
#pragma unroll
    for (int k = 0; k < K; ++k) {
        float w = Ws[k * F + f];
        acc0 = fmaf(r0[k], w, acc0);
        acc1 = fmaf(r1[k], w, acc1);
        acc2 = fmaf(r2[k], w, acc2);
        acc3 = fmaf(r3[k], w, acc3);
    }
    if (RELU_BIAS) {
        float b = bias[f];
        out[(long)n0 * F + f]        = fmaxf(acc0 + b, 0.f);
        out[(long)(n0 + 4) * F + f]  = fmaxf(acc1 + b, 0.f);
        out[(long)(n0 + 8) * F + f]  = fmaxf(acc2 + b, 0.f);
        out[(long)(n0 + 12) * F + f] = fmaxf(acc3 + b, 0.f);
    } else {
        out[(long)n0 * F + f]        = dinv[n0] * acc0;
        out[(long)(n0 + 4) * F + f]  = dinv[n0 + 4] * acc1;
        out[(long)(n0 + 8) * F + f]  = dinv[n0 + 8] * acc2;
        out[(long)(n0 + 12) * F + f] = dinv[n0 + 12] * acc3;
    }
}

// ---------------- head: out = relu(pooled/cnt @ lw1 + lb1) @ lw2 + lb2 ----------------
__global__ void head_kernel(const float* __restrict__ pooled, const float* __restrict__ counts,
                            const float* __restrict__ lw1, const float* __restrict__ lb1,
                            const float* __restrict__ lw2, const float* __restrict__ lb2,
                            float* __restrict__ out) {
    __shared__ float p[F];
    __shared__ float hid[F];
    int gid = blockIdx.x, t = threadIdx.x;
    float cnt = fmaxf(counts[gid], 1.0f);
    p[t] = pooled[(long)gid * F + t] / cnt;
    __syncthreads();
    float acc = lb1[t];
#pragma unroll 8
    for (int k = 0; k < F; ++k) acc = fmaf(p[k], lw1[k * F + t], acc);
    hid[t] = fmaxf(acc, 0.f);
    __syncthreads();
    if (t < 2) {
        float a = lb2[t];
#pragma unroll 8
        for (int k = 0; k < F; ++k) a = fmaf(hid[k], lw2[k * 2 + t], a);
        out[(long)gid * 2 + t] = a;
    }
}

extern "C" void kernel_launch(void* const* d_in, const int* in_sizes, int n_in,
                              void* d_out, int out_size, void* d_ws, size_t ws_size,
                              hipStream_t stream) {
    const float* x    = (const float*)d_in[0];
    const int*   ei   = (const int*)d_in[1];   // [2, NE]: src then dst
    const int*   bat  = (const int*)d_in[2];
    const float* W1   = (const float*)d_in[3];
    const float* b1   = (const float*)d_in[4];
    const float* W2   = (const float*)d_in[5];
    const float* b2   = (const float*)d_in[6];
    const float* W3   = (const float*)d_in[7];
    const float* b3   = (const float*)d_in[8];
    const float* lw1  = (const float*)d_in[9];
    const float* lb1  = (const float*)d_in[10];
    const float* lw2  = (const float*)d_in[11];
    const float* lb2  = (const float*)d_in[12];
    float* out = (float*)d_out;

    const int* src = ei;
    const int* dst = ei + NE;

    // workspace carve-up (256B aligned)
    char* ws = (char*)d_ws;
    size_t off = 0;
    auto carve = [&](size_t bytes) {
        void* p = ws + off;
        off += (bytes + 255) & ~(size_t)255;
        return p;
    };
    int*   deg     = (int*)carve(NN * 4);
    float* dinv    = (float*)carve(NN * 4);
    int*   rowptr  = (int*)carve((NN + 1) * 4);
    int*   cursor  = (int*)carve(NN * 4);
    int*   bsums   = (int*)carve(256 * 4);
    int*   col     = (int*)carve((size_t)NE * 4);
    float* xd      = (float*)carve((size_t)NN * 32 * 4);
    float* sbuf    = (float*)carve((size_t)NN * 32 * 4);
    float* bufA    = (float*)carve((size_t)NN * F * 4);
    float* bufB    = (float*)carve((size_t)NN * F * 4);
    float* pooled  = (float*)carve((size_t)NG * F * 4 + NG * 4);
    float* counts  = pooled + (size_t)NG * F;

    hipMemsetAsync(deg, 0, NN * 4, stream);
    hipMemsetAsync(pooled, 0, ((size_t)NG * F + NG) * 4, stream);

    deg_kernel<<<(NE + 255) / 256, 256, 0, stream>>>(dst, deg);
    dinv_kernel<<<NB, 256, 0, stream>>>(deg, dinv);
    scalex_kernel<<<(NN * 8 + 255) / 256, 256, 0, stream>>>((const float4*)x, dinv, (float4*)xd);
    scan1_kernel<<<NB, 256, 0, stream>>>(deg, bsums);
    scan2_kernel<<<1, 256, 0, stream>>>(bsums, rowptr);
    scan3_kernel<<<NB, 256, 0, stream>>>(deg, bsums, rowptr, cursor);
    fill_kernel<<<(NE + 255) / 256, 256, 0, stream>>>(src, dst, cursor, col);

    const int gridN = (NN + 3) / 4;    // 12500 blocks, 4 nodes (waves) each
    const int gridG = NN / 16;         // 3125 blocks for gemm

    // layer 1: aggregate raw 32-feat xd, then GEMM with fused bias+relu
    agg32_kernel<<<gridN, 256, 0, stream>>>((const f4*)xd, rowptr, col, dinv, sbuf);
    gemm_kernel<32, true><<<gridG, 256, 0, stream>>>(sbuf, W1, b1, dinv, bufA);

    // layer 2: g = dinv*(h1@W2), aggregate with bias+relu
    gemm_kernel<64, false><<<gridG, 256, 0, stream>>>(bufA, W2, nullptr, dinv, bufB);
    agg4_kernel<false><<<gridN, 256, 0, stream>>>((const f4*)bufB, rowptr, col, dinv,
                                                  (const f4*)b2, bufA,
                                                  nullptr, nullptr, nullptr);
    // layer 3: fused mean-pool accumulation
    gemm_kernel<64, false><<<gridG, 256, 0, stream>>>(bufA, W3, nullptr, dinv, bufB);
    agg4_kernel<true><<<gridN, 256, 0, stream>>>((const f4*)bufB, rowptr, col, dinv,
                                                 (const f4*)b3, nullptr,
                                                 bat, pooled, counts);
    // head MLP
    head_kernel<<<NG, 64, 0, stream>>>(pooled, counts, lw1, lb1, lw2, lb2, out);
}